// Round 7
// baseline (240.182 us; speedup 1.0000x reference)
//
#include <hip/hip_runtime.h>
#include <stdint.h>

// All buffers f32 (round-4: bit-exact f32 pipeline passed, absmax 0.0).
// Timed window contains ~165 us of harness poison fills (877 MB d_ws fill at
// ~132 us visible in rocprof each iteration) — our kernels are the remainder.
#define NYv 496
#define NXv 432
#define Cv  64
#define Bv  4
#define PLANE (NYv * NXv)            // 214272 elements per (b,c) plane
#define NVEC (NXv / 4)               // 108 float4 vectors per canvas row
#define ROWS (Bv * NYv)              // 1984 canvas rows
#define UNITS (ROWS * NVEC)          // 214272 vec-units == 837 * 256 exactly
#define CSPLIT 2
#define CCHUNK (Cv / CSPLIT)         // 32 channels per gather thread

// Native clang vectors — __builtin_nontemporal_store rejects HIP_vector_type.
typedef float  f32x4 __attribute__((ext_vector_type(4)));
typedef int    i32x4 __attribute__((ext_vector_type(4)));

// K1: scatter pillar index i into canvas[(b*NY + y)*NX + x].
// Canvas pre-set to -1 (memset 0xFF) so unoccupied cells read <0.
__global__ __launch_bounds__(256) void scatter_idx(const int4* __restrict__ coords,
                                                   int* __restrict__ canvas, int n) {
    int i = blockIdx.x * 256 + threadIdx.x;
    if (i >= n) return;
    int4 c4 = coords[i];             // (b, z, y, x)
    canvas[((size_t)c4.x * NYv + c4.z) * NXv + c4.w] = i;
}

__device__ __forceinline__ f32x4 pack4(const float* __restrict__ feats,
                                       const int* p, int c) {
    f32x4 f;
    f.x = (p[0] >= 0) ? feats[(size_t)p[0] * Cv + c] : 0.0f;
    f.y = (p[1] >= 0) ? feats[(size_t)p[1] * Cv + c] : 0.0f;
    f.z = (p[2] >= 0) ? feats[(size_t)p[2] * Cv + c] : 0.0f;
    f.w = (p[3] >= 0) ? feats[(size_t)p[3] * Cv + c] : 0.0f;
    return f;
}

// K2: inverse gather, full-lane linear mapping. Thread u owns vec-unit u of
// the 1984x108 (row x float4) canvas space — grid.x = 837 covers it exactly
// (837*256 == 214272), every lane active. One int4 canvas load per thread,
// then 32 coalesced float4 stores (one per channel of this block's chunk).
// Stores are nontemporal: 219 MB write-once data skips L2 retention, leaving
// L2 to canvas re-reads and the rare (5.6% occupancy) feature-line fetches.
// Within a wave consecutive u => consecutive plane offsets => each store
// instruction covers 1024 contiguous bytes.
__global__ __launch_bounds__(256) void gather_all(const float* __restrict__ feats,
                                                  const int* __restrict__ canvas,
                                                  float* __restrict__ out) {
    int u = blockIdx.x * 256 + (int)threadIdx.x;   // 0..214271, exact cover
    int g = u / NVEC;                              // canvas row 0..1983
    int v = u - g * NVEC;                          // 0..107
    int b = g / NYv;
    int y = g - b * NYv;
    int c0 = blockIdx.y * CCHUNK;

    i32x4 pi = *reinterpret_cast<const i32x4*>(canvas + (size_t)g * NXv + v * 4);
    int p[4] = {pi.x, pi.y, pi.z, pi.w};

    float* outp = out + ((size_t)(b * Cv + c0)) * PLANE + y * NXv + v * 4;
#pragma unroll 8
    for (int c = 0; c < CCHUNK; ++c) {
        f32x4 f = pack4(feats, p, c0 + c);
        __builtin_nontemporal_store(f, reinterpret_cast<f32x4*>(outp + (size_t)c * PLANE));
    }
}

extern "C" void kernel_launch(void* const* d_in, const int* in_sizes, int n_in,
                              void* d_out, int out_size, void* d_ws, size_t ws_size,
                              hipStream_t stream) {
    const float* feats  = (const float*)d_in[0];   // f32, [N, 64]
    const int*   coords = (const int*)d_in[1];     // int32, [N, 4]
    int n = in_sizes[0] / Cv;                      // 48000 pillars
    float* out    = (float*)d_out;
    int*   canvas = (int*)d_ws;                    // 3.43 MB of ~877 MB ws

    // -1 sentinel (0xAA poison is also negative, but don't rely on it).
    (void)hipMemsetAsync(canvas, 0xFF, (size_t)Bv * PLANE * sizeof(int), stream);

    scatter_idx<<<(n + 255) / 256, 256, 0, stream>>>((const int4*)coords, canvas, n);

    dim3 gmain(UNITS / 256, CSPLIT);               // (837, 2) — exact cover
    gather_all<<<gmain, 256, 0, stream>>>(feats, canvas, out);
}

// Round 8
// 229.045 us; speedup vs baseline: 1.0486x; 1.0486x over previous
//
#include <hip/hip_runtime.h>
#include <stdint.h>

// All buffers f32. Timed window carries ~170 us of harness poison fills
// (877 MB ws fill @ ~132 us + 219 MB out fill @ ~33 us, visible in rocprof
// every iteration); our 3 dispatches are the ~60 us remainder.
// Config history: r5 plain/CSPLIT4 = 231.0 | r4 = 233.6 | r7 nt/CSPLIT2 = 240.2
// -> plain stores (the 6.6 TB/s harness fill uses plain stores too), CSPLIT 4.
#define NYv 496
#define NXv 432
#define Cv  64
#define Bv  4
#define PLANE (NYv * NXv)            // 214272 elements per (b,c) plane
#define NVEC (NXv / 4)               // 108 float4 vectors per canvas row
#define ROWS (Bv * NYv)              // 1984 canvas rows
#define UNITS (ROWS * NVEC)          // 214272 vec-units == 837 * 256 exactly
#define CSPLIT 4
#define CCHUNK (Cv / CSPLIT)         // 16 channels per gather thread

typedef float  f32x4 __attribute__((ext_vector_type(4)));
typedef int    i32x4 __attribute__((ext_vector_type(4)));

// K1: scatter pillar index i into canvas[(b*NY + y)*NX + x].
// Canvas pre-set to -1 (memset 0xFF) so unoccupied cells read <0.
__global__ __launch_bounds__(256) void scatter_idx(const int4* __restrict__ coords,
                                                   int* __restrict__ canvas, int n) {
    int i = blockIdx.x * 256 + threadIdx.x;
    if (i >= n) return;
    int4 c4 = coords[i];             // (b, z, y, x)
    canvas[((size_t)c4.x * NYv + c4.z) * NXv + c4.w] = i;
}

// K2: inverse gather, full-lane exact-cover mapping (837*256 == 214272 units).
// Per thread: one int4 canvas load -> 4 pillar indices; then per 4-channel
// group, ONE exec-masked f32x4 feature load per pillar (rows are contiguous,
// 16B-aligned) register-transposed into 4 coalesced float4 plane stores.
// VMEM issue per 1KB-wave-store drops 5 -> 2 vs the per-channel scalar-load
// version; empty lanes (94%) skip feature loads entirely via exec mask.
__global__ __launch_bounds__(256) void gather_all(const float* __restrict__ feats,
                                                  const int* __restrict__ canvas,
                                                  float* __restrict__ out) {
    int u = blockIdx.x * 256 + (int)threadIdx.x;   // 0..214271
    int g = u / NVEC;                              // canvas row 0..1983
    int v = u - g * NVEC;                          // 0..107
    int b = g / NYv;
    int y = g - b * NYv;
    int c0 = blockIdx.y * CCHUNK;

    i32x4 pi = *reinterpret_cast<const i32x4*>(canvas + (size_t)g * NXv + v * 4);
    int p[4] = {pi.x, pi.y, pi.z, pi.w};

    float* outp = out + ((size_t)(b * Cv + c0)) * PLANE + y * NXv + v * 4;

#pragma unroll
    for (int cg = 0; cg < CCHUNK / 4; ++cg) {      // 4 groups of 4 channels
        f32x4 w[4] = {{0,0,0,0}, {0,0,0,0}, {0,0,0,0}, {0,0,0,0}};
#pragma unroll
        for (int j = 0; j < 4; ++j) {
            if (p[j] >= 0)                         // exec-masked vector load
                w[j] = *reinterpret_cast<const f32x4*>(
                    feats + (size_t)p[j] * Cv + c0 + cg * 4);
        }
#pragma unroll
        for (int k = 0; k < 4; ++k) {              // transpose: channel k of group
            f32x4 f;
            f.x = w[0][k]; f.y = w[1][k]; f.z = w[2][k]; f.w = w[3][k];
            *reinterpret_cast<f32x4*>(outp + (size_t)(cg * 4 + k) * PLANE) = f;
        }
    }
}

extern "C" void kernel_launch(void* const* d_in, const int* in_sizes, int n_in,
                              void* d_out, int out_size, void* d_ws, size_t ws_size,
                              hipStream_t stream) {
    const float* feats  = (const float*)d_in[0];   // f32, [N, 64]
    const int*   coords = (const int*)d_in[1];     // int32, [N, 4]
    int n = in_sizes[0] / Cv;                      // 48000 pillars
    float* out    = (float*)d_out;
    int*   canvas = (int*)d_ws;                    // 3.43 MB of ~877 MB ws

    // -1 sentinel (0xAA poison is also negative, but don't rely on it).
    (void)hipMemsetAsync(canvas, 0xFF, (size_t)Bv * PLANE * sizeof(int), stream);

    scatter_idx<<<(n + 255) / 256, 256, 0, stream>>>((const int4*)coords, canvas, n);

    dim3 gmain(UNITS / 256, CSPLIT);               // (837, 4) — exact cover
    gather_all<<<gmain, 256, 0, stream>>>(feats, canvas, out);
}